// Round 9
// baseline (293.268 us; speedup 1.0000x reference)
//
#include <hip/hip_runtime.h>
#include <hip/hip_bf16.h>
#include <stdint.h>

#define B_ 4
#define T_ 512
#define H_ 32
#define N_ 64
#define D_ 2048
#define M_ (B_*T_)

typedef __attribute__((ext_vector_type(4))) float f32x4;
typedef __attribute__((ext_vector_type(8))) short short8;

// DPP butterfly add across 16-lane groups: pure VALU.
template <int CTRL>
__device__ __forceinline__ float dpp_add(float x) {
    int t = __builtin_amdgcn_mov_dpp(__float_as_int(x), CTRL, 0xF, 0xF, true);
    return x + __int_as_float(t);
}
__device__ __forceinline__ float bfly16(float x) {
    x = dpp_add<0xB1>(x);    // xor1
    x = dpp_add<0x4E>(x);    // xor2
    x = dpp_add<0x141>(x);   // xor4 row_half_mirror
    x = dpp_add<0x140>(x);   // xor8 row_mirror
    return x;
}

__device__ __forceinline__ void gld16(const void* g, void* l) {
    __builtin_amdgcn_global_load_lds(
        (const __attribute__((address_space(1))) unsigned int*)g,
        (__attribute__((address_space(3))) unsigned int*)l, 16, 0, 0);
}

__device__ __forceinline__ uint f2bf(float x) {   // RNE f32->bf16 (low 16)
    uint u = __float_as_uint(x);
    return (u + 0x7fffu + ((u >> 16) & 1u)) >> 16;
}

// ---------------------------------------------------------------------------
// Kernel 1: precompute+pack streams, 1024B per (bh,t):
//   [RK: 64 x {bf16 r lo, bf16 k hi} = 256B][AB: {bf16 kk lo, bf16 bb hi}]
//   [D: 64 f32][V: 64 f32]
// R9: bf16 for the 4 broadcast (non-compounding) streams. Decay stays f32
// (512-step compounding), v stays f32 (row-indexed). R4 proved numerics
// safe (absmax bit-identical); R4's perf regression was the old structure.
// ---------------------------------------------------------------------------
__global__ __launch_bounds__(256) void prep(
    const float* __restrict__ r, const float* __restrict__ w,
    const float* __restrict__ k, const float* __restrict__ v,
    const float* __restrict__ iclr, char* __restrict__ pk) {
    int g = blockIdx.x * 4 + (threadIdx.x >> 6);   // (b,t,h) flat index
    int lane = threadIdx.x & 63;
    int b = g >> 14;             // / (T*H)
    int t = (g >> 5) & (T_ - 1); // / H % T
    int h = g & 31;              // % H
    size_t si = (size_t)g * 64 + lane;
    char* dst = pk + ((size_t)(b * H_ + h) * T_ + t) * 1024;
    float rv = r[si], wv = w[si], kv = k[si], vv = v[si], av = iclr[si];
    float d = expf(-expf(wv));
    float ss = kv * kv;
#pragma unroll
    for (int m = 1; m < 64; m <<= 1) ss += __shfl_xor(ss, m, 64);
    float kkv = kv * rsqrtf(ss + 1e-12f);
    float bbv = kkv * (1.f / (1.f + expf(-av)));
    uint rk = f2bf(rv)  | (f2bf(kv)  << 16);
    uint ab = f2bf(kkv) | (f2bf(bbv) << 16);
    *(uint*) (dst +       lane * 4) = rk;
    *(uint*) (dst + 256 + lane * 4) = ab;
    *(float*)(dst + 512 + lane * 4) = d;
    *(float*)(dst + 768 + lane * 4) = vv;
}

// ---------------------------------------------------------------------------
// Kernel 2: WKV-7 scan, sibling-merged (R6 structure, 124us proven) +
// bf16-packed streams. R8 counters: VALUBusy 38% (215/565 cyc/step/SIMD),
// idle = lgkm waits; per-CU LDS-read demand 8 waves x 66 cyc ~= the 565
// wall -> LDS-return-pipe saturated. Packing cuts reads to 8 x 42
// (2xb128 packed + 1xb128 D + 1xb32 v) and DMA to 4KB/group.
// wave0 vmcnt ledger (4 DMA + 4 st per group): top of group g outstanding
// = [4 st g-1][4 DMA g+1]; data-g DMAs older -> vmcnt(8). g==0: vmcnt(4).
// Refill of slot g&1 (data g+2) after barrier2. Blocks >= 256: dequant.
// ---------------------------------------------------------------------------
__global__ __launch_bounds__(512) void wkv_scan(
    const char* __restrict__ pk, __hip_bfloat16* __restrict__ y,
    const int* __restrict__ q, __hip_bfloat16* __restrict__ o) {
    if (blockIdx.x >= 256) {       // ---- weight dequant part ----
        int i = ((blockIdx.x - 256) * 512 + (int)threadIdx.x) * 4;
        int4 qi = *(const int4*)(q + i);
        __hip_bfloat16 t[4];
        t[0] = __float2bfloat16((float)qi.x);
        t[1] = __float2bfloat16((float)qi.y);
        t[2] = __float2bfloat16((float)qi.z);
        t[3] = __float2bfloat16((float)qi.w);
        *(uint2*)(o + i) = *(uint2*)t;
        return;
    }
    const int bh   = blockIdx.x & 127;
    const int half = blockIdx.x >> 7;
    const int tid  = threadIdx.x;
    const int wave = tid >> 6;
    const int lane = tid & 63;
    const int b = bh >> 5, h = bh & 31;
    const int jg = lane & 15;
    const int rl = lane >> 4;
    const int row = (half * 8 + wave) * 4 + rl;

    __shared__ __align__(16) char ring[2 * 4096];   // 8 KB, shared by 8 waves

    const char* src = pk + (size_t)bh * T_ * 1024;

    // prologue: producer fills both superslots (8 DMAs outstanding)
    if (wave == 0) {
#pragma unroll
        for (int gg = 0; gg < 2; ++gg)
#pragma unroll
            for (int i = 0; i < 4; ++i)
                gld16(src + (gg * 4 + i) * 1024 + lane * 16,
                      &ring[gg * 4096 + i * 1024]);
    }

    float S[4] = {0.f, 0.f, 0.f, 0.f};

    for (int g = 0; g < T_ / 4; ++g) {
        if (wave == 0) {
            if (g == 0) { asm volatile("s_waitcnt vmcnt(4)" ::: "memory"); }
            else        { asm volatile("s_waitcnt vmcnt(8)" ::: "memory"); }
        }
        asm volatile("s_barrier" ::: "memory");   // slot g&1 holds data g
        const char* rb0 = &ring[(g & 1) * 4096];

#pragma unroll
        for (int i = 0; i < 4; ++i) {
            const int t = g * 4 + i;
            const char* rb = rb0 + i * 1024;

            uint4 rk  = *(const uint4*)(rb +       jg * 16);
            uint4 ab  = *(const uint4*)(rb + 256 + jg * 16);
            f32x4 Dc  = *(const f32x4*)(rb + 512 + jg * 16);
            float vcv = *(const float*)(rb + 768 + row * 4);

            float R[4], K[4], A[4], Bv[4];
            uint rr[4] = {rk.x, rk.y, rk.z, rk.w};
            uint aa[4] = {ab.x, ab.y, ab.z, ab.w};
#pragma unroll
            for (int j = 0; j < 4; ++j) {
                R[j]  = __uint_as_float(rr[j] << 16);
                K[j]  = __uint_as_float(rr[j] & 0xffff0000u);
                A[j]  = __uint_as_float(aa[j] << 16);
                Bv[j] = __uint_as_float(aa[j] & 0xffff0000u);
            }

            // sa = -(S_old . kk)
            float s01 = fmaf(S[1], A[1], S[0] * A[0]);
            float s23 = fmaf(S[3], A[3], S[2] * A[2]);
            const float sa = -bfly16(s01 + s23);

            // S = S*dec + sa*bb + v*k ;  y partial = S_new . r
            float t0 = fmaf(sa, Bv[0], vcv * K[0]);
            S[0] = fmaf(S[0], Dc[0], t0);
            float t1 = fmaf(sa, Bv[1], vcv * K[1]);
            S[1] = fmaf(S[1], Dc[1], t1);
            float y01 = fmaf(S[1], R[1], S[0] * R[0]);
            float t2 = fmaf(sa, Bv[2], vcv * K[2]);
            S[2] = fmaf(S[2], Dc[2], t2);
            float t3 = fmaf(sa, Bv[3], vcv * K[3]);
            S[3] = fmaf(S[3], Dc[3], t3);
            float y23 = fmaf(S[3], R[3], S[2] * R[2]);
            float ys = bfly16(y01 + y23);
            if (jg == 0)
                y[((size_t)b * T_ + t) * D_ + h * 64 + row] = __float2bfloat16(ys);
        }

        asm volatile("s_barrier" ::: "memory");   // all done reading slot g&1

        if (wave == 0) {
            // refill slot g&1 with group g+2 (clamped tail re-reads: harmless)
            int gp = g + 2; if (gp > T_ / 4 - 1) gp = T_ / 4 - 1;
#pragma unroll
            for (int i = 0; i < 4; ++i)
                gld16(src + ((size_t)gp * 4 + i) * 1024 + lane * 16,
                      &ring[(g & 1) * 4096 + i * 1024]);
        }
    }
}

// ---------------------------------------------------------------------------
// Kernel 3: C[m,o] = scale[o] * sum_d Y[m,d] * Wq[o,d]  (B^T GEMM)
// R8 version verbatim (passed; swizzle verified by absmax parity).
// 128x128, counted-vmcnt 2-phase, T2 both-sides swizzle, XCD-bijective grid.
// ---------------------------------------------------------------------------
__device__ __forceinline__ void gload_lds16(const __hip_bfloat16* g, ushort* l) {
    __builtin_amdgcn_global_load_lds(
        (const __attribute__((address_space(1))) unsigned int*)g,
        (__attribute__((address_space(3))) unsigned int*)l, 16, 0, 0);
}

__global__ __launch_bounds__(256, 1) void gemm_bt(
    const __hip_bfloat16* __restrict__ A,   // [M, K]
    const __hip_bfloat16* __restrict__ Bq,  // [N, K]
    const float* __restrict__ scale,        // [N]
    float* __restrict__ C) {                // [M, N]
    const int K = D_;
    __shared__ __align__(16) ushort As[2][128 * 64];   // 32 KB
    __shared__ __align__(16) ushort Bs[2][128 * 64];   // 32 KB

    const int tid = threadIdx.x;
    const int lane = tid & 63;
    const int wave = tid >> 6;
    const int wr = wave >> 1, wc = wave & 1;

    const int id = blockIdx.x;
    const int swz = (id & 7) * 32 + (id >> 3);
    const int m0 = (swz & 15) * 128;
    const int n0 = (swz >> 4) * 128;

    const int srow8 = lane >> 3;
    const int scolS = (((lane & 7) ^ (lane >> 3)) * 8);  // pre-swizzled src col
    const int ml = lane & 15;
    const int q4 = lane >> 4;
    const int m7 = ml & 7;

    f32x4 acc[4][4] = {};

#define GSTAGE(slot, kk0)                                                    \
    {                                                                        \
        _Pragma("unroll")                                                    \
        for (int c = 0; c < 4; ++c) {                                        \
            int ra = wave * 32 + c * 8;                                      \
            gload_lds16(A + (size_t)(m0 + ra + srow8) * K + (kk0) + scolS,   \
                        &As[slot][ra * 64]);                                 \
            gload_lds16(Bq + (size_t)(n0 + ra + srow8) * K + (kk0) + scolS,  \
                        &Bs[slot][ra * 64]);                                 \
        }                                                                    \
    }

    GSTAGE(0, 0);                         // prologue: stage tile 0

    for (int t = 0; t < K / 64; ++t) {
        if (t + 1 < K / 64) {
            GSTAGE((t + 1) & 1, (t + 1) * 64);   // issue next tile's DMAs
            asm volatile("s_waitcnt vmcnt(8)" ::: "memory");  // tile t landed
        } else {
            asm volatile("s_waitcnt vmcnt(0)" ::: "memory");
        }
        asm volatile("s_barrier" ::: "memory");
        const int sl = t & 1;
#pragma unroll
        for (int ks = 0; ks < 2; ++ks) {
            const int blk = ((ks * 4 + q4) ^ m7) * 8;   // swizzled read col
            short8 af[4], bf[4];
#pragma unroll
            for (int tm = 0; tm < 4; ++tm)
                af[tm] = *(const short8*)(&As[sl][(wr * 64 + tm * 16 + ml) * 64 + blk]);
#pragma unroll
            for (int tn = 0; tn < 4; ++tn)
                bf[tn] = *(const short8*)(&Bs[sl][(wc * 64 + tn * 16 + ml) * 64 + blk]);
#pragma unroll
            for (int tm = 0; tm < 4; ++tm)
#pragma unroll
                for (int tn = 0; tn < 4; ++tn)
                    acc[tm][tn] = __builtin_amdgcn_mfma_f32_16x16x32_bf16(
                        af[tm], bf[tn], acc[tm][tn], 0, 0, 0);
        }
        asm volatile("s_barrier" ::: "memory");   // done reading slot sl
    }
#undef GSTAGE

#pragma unroll
    for (int tn = 0; tn < 4; ++tn) {
        int gn = n0 + wc * 64 + tn * 16 + ml;
        float sc = scale[gn];
#pragma unroll
        for (int tm = 0; tm < 4; ++tm) {
            int gm = m0 + wr * 64 + tm * 16 + (lane >> 4) * 4;
#pragma unroll
            for (int rg = 0; rg < 4; ++rg)
                C[(size_t)(gm + rg) * D_ + gn] = acc[tm][tn][rg] * sc;
        }
    }
}

// ---------------------------------------------------------------------------
extern "C" void kernel_launch(void* const* d_in, const int* in_sizes, int n_in,
                              void* d_out, int out_size, void* d_ws, size_t ws_size,
                              hipStream_t stream) {
    (void)in_sizes; (void)n_in; (void)out_size; (void)ws_size;
    const float* r  = (const float*)d_in[0];
    const float* w  = (const float*)d_in[1];
    const float* k  = (const float*)d_in[2];
    const float* v  = (const float*)d_in[3];
    const float* ic = (const float*)d_in[4];
    const int*   wq = (const int*)d_in[5];
    const float* sc = (const float*)d_in[6];
    float* out = (float*)d_out;

    // ws: yb 8.4MB | wb 8.4MB | pk (packed streams, 1KB/step) 67MB
    char* p = (char*)d_ws;
    __hip_bfloat16* yb = (__hip_bfloat16*)p;  p += (size_t)M_ * D_ * 2;
    __hip_bfloat16* wb = (__hip_bfloat16*)p;  p += (size_t)D_ * D_ * 2;
    char* pk = p;

    prep    <<<dim3(16384), dim3(256), 0, stream>>>(r, w, k, v, ic, pk);
    wkv_scan<<<dim3(256 + 2048), dim3(512), 0, stream>>>(pk, yb, wq, wb);
    gemm_bt <<<dim3(256), dim3(256), 0, stream>>>(yb, wb, sc, out);
}